// Round 1
// baseline (497.736 us; speedup 1.0000x reference)
//
#include <hip/hip_runtime.h>

#define LRES 128
#define HRES 1024
#define NB 256        // hist/scatter blocks
#define BTS 1024      // threads for big blocks
#define NBUCK 512     // coarse buckets (Morton top 9 bits of 128^3 lattice)
#define RCAP 8192     // refine in-register cap per bucket (avg ~3906)

static const int LVOX = LRES * LRES * LRES; // 2,097,152
static const int PPIX = HRES * HRES;        // 1,048,576
static const int TV = LVOX + 3 * PPIX;      // 5,242,880 transpose elems

typedef float f32x4 __attribute__((ext_vector_type(4)));
typedef unsigned u32x4 __attribute__((ext_vector_type(4)));

// ---------- helpers ----------

// Replicates reference _to_idx exactly.
__device__ __forceinline__ void to_idx(float c, int size, int& i0, int& i1, float& w) {
    float p = (c + 1.0f) * 0.5f * (float)(size - 1);
    float f = floorf(p);
    w = p - f;
    int i = (int)f;
    i0 = min(max(i, 0), size - 1);
    i1 = min(i0 + 1, size - 1);
}

// float -> bf16 (RNE)
__device__ __forceinline__ unsigned f2bf(float f) {
    unsigned u = __float_as_uint(f);
    return (u + 0x7FFFu + ((u >> 16) & 1u)) >> 16;
}
__device__ __forceinline__ float bflo(unsigned u) { return __uint_as_float(u << 16); }
__device__ __forceinline__ float bfhi(unsigned u) { return __uint_as_float(u & 0xFFFF0000u); }

__device__ __forceinline__ void fma8u(f32x4& a0, f32x4& a1, uint4 q, float w) {
    a0.x = fmaf(bflo(q.x), w, a0.x);
    a0.y = fmaf(bfhi(q.x), w, a0.y);
    a0.z = fmaf(bflo(q.y), w, a0.z);
    a0.w = fmaf(bfhi(q.y), w, a0.w);
    a1.x = fmaf(bflo(q.z), w, a1.x);
    a1.y = fmaf(bfhi(q.z), w, a1.y);
    a1.z = fmaf(bflo(q.w), w, a1.z);
    a1.w = fmaf(bfhi(q.w), w, a1.w);
}

__device__ __forceinline__ unsigned spread3(unsigned x) {
    x &= 0x3FFu;
    x = (x | (x << 16)) & 0x030000FFu;
    x = (x | (x << 8)) & 0x0300F00Fu;
    x = (x | (x << 4)) & 0x030C30C3u;
    x = (x | (x << 2)) & 0x09249249u;
    return x;
}
// 21-bit Morton on a 128^3 lattice over [0,1)^3. bucket = >>12, fine = &4095.
__device__ __forceinline__ unsigned morton21(float x, float y, float z) {
    int px = min(max((int)(x * 128.f), 0), 127);
    int py = min(max((int)(y * 128.f), 0), 127);
    int pz = min(max((int)(z * 128.f), 0), 127);
    return spread3(px) | (spread3(py) << 1) | (spread3(pz) << 2);
}

// ---------- fused prep: blocks [0,NB) = bucket histogram, rest = transpose ----------
// hmat is BUCKET-major: hmat[c * NB + b] (contiguous per-bucket rows for the scan).
__global__ __launch_bounds__(BTS) void prep_k(const float* __restrict__ xyz,
                                              const int* __restrict__ boundp,
                                              const float* __restrict__ Lg,
                                              const float* __restrict__ Hp,
                                              unsigned* __restrict__ hmat,
                                              u32x4* __restrict__ gclb,
                                              u32x4* __restrict__ pclb, int N) {
    __shared__ unsigned h[NBUCK];
    int b = blockIdx.x;
    if (b < NB) {
        for (int i = threadIdx.x; i < NBUCK; i += BTS) h[i] = 0u;
        __syncthreads();
        float invb = 1.0f / (float)boundp[0];
        int NG = (N + 3) >> 2; // 4-point groups
        for (int g = b * BTS + threadIdx.x; g < NG; g += NB * BTS) {
            int n0 = g << 2;
            if (n0 + 4 <= N) {
                // 3 x dwordx4 = 12 floats = 4 points, all loads independent
                f32x4 qa = *(const f32x4*)(xyz + (size_t)n0 * 3);
                f32x4 qb = *(const f32x4*)(xyz + (size_t)n0 * 3 + 4);
                f32x4 qc = *(const f32x4*)(xyz + (size_t)n0 * 3 + 8);
                atomicAdd(&h[morton21(qa.x * invb, qa.y * invb, qa.z * invb) >> 12], 1u);
                atomicAdd(&h[morton21(qa.w * invb, qb.x * invb, qb.y * invb) >> 12], 1u);
                atomicAdd(&h[morton21(qb.z * invb, qb.w * invb, qc.x * invb) >> 12], 1u);
                atomicAdd(&h[morton21(qc.y * invb, qc.z * invb, qc.w * invb) >> 12], 1u);
            } else {
                for (int n = n0; n < N; ++n) {
                    float x = xyz[(size_t)3 * n + 0] * invb;
                    float y = xyz[(size_t)3 * n + 1] * invb;
                    float z = xyz[(size_t)3 * n + 2] * invb;
                    atomicAdd(&h[morton21(x, y, z) >> 12], 1u);
                }
            }
        }
        __syncthreads();
        for (int i = threadIdx.x; i < NBUCK; i += BTS)
            hmat[(size_t)i * NB + b] = h[i];
    } else {
        // transpose: FOUR channels-last bf16 elements per thread.
        // Load all 8 channel float4s into registers FIRST (8 loads in flight),
        // then convert+pack — forces MLP instead of load->use serialization.
        int v = ((b - NB) * BTS + threadIdx.x) * 4;
        if (v >= TV) return;
        f32x4 f[8];
        u32x4* dst;
        if (v < LVOX) {
#pragma unroll
            for (int c = 0; c < 8; ++c)
                f[c] = __builtin_nontemporal_load((const f32x4*)(Lg + (size_t)c * LVOX + v));
            dst = gclb + v;
        } else {
            int u = v - LVOX;
            int p = u >> 20;
            int r = u & (PPIX - 1);
            const float* src = Hp + (size_t)p * 8 * PPIX + r;
#pragma unroll
            for (int c = 0; c < 8; ++c)
                f[c] = __builtin_nontemporal_load((const f32x4*)(src + (size_t)c * PPIX));
            dst = pclb + (size_t)p * PPIX + r;
        }
#pragma unroll
        for (int e = 0; e < 4; ++e) {
            u32x4 o;
            o.x = f2bf(f[0][e]) | (f2bf(f[1][e]) << 16);
            o.y = f2bf(f[2][e]) | (f2bf(f[3][e]) << 16);
            o.z = f2bf(f[4][e]) | (f2bf(f[5][e]) << 16);
            o.w = f2bf(f[6][e]) | (f2bf(f[7][e]) << 16);
            __builtin_nontemporal_store(o, dst + e);
        }
    }
}

// Single block: cross-block prefix per bucket (in place, bucket-major rows so
// each thread streams a contiguous 1KB row via uint4 with 8 loads in flight),
// scan bucket totals, emit bucket_base[NBUCK+1], add base into hmat.
__global__ __launch_bounds__(1024) void offsets_k(unsigned* __restrict__ hmat,
                                                  unsigned* __restrict__ bb) {
    __shared__ unsigned tot[NBUCK];
    __shared__ unsigned cbase[NBUCK];
    int t = threadIdx.x;
    unsigned run = 0;
    if (t < NBUCK) {
        u32x4* row = (u32x4*)(hmat + (size_t)t * NB);
        for (int ch = 0; ch < NB / 32; ++ch) { // 8 chunks of 8 uint4 = 256 vals
            u32x4 q[8];
#pragma unroll
            for (int k = 0; k < 8; ++k) q[k] = row[ch * 8 + k];
#pragma unroll
            for (int k = 0; k < 8; ++k) {
                unsigned v0 = q[k].x, v1 = q[k].y, v2 = q[k].z, v3 = q[k].w;
                q[k].x = run; run += v0;
                q[k].y = run; run += v1;
                q[k].z = run; run += v2;
                q[k].w = run; run += v3;
                row[ch * 8 + k] = q[k];
            }
        }
        tot[t] = run;
    }
    __syncthreads();
    for (int o = 1; o < NBUCK; o <<= 1) {
        unsigned v = 0;
        if (t < NBUCK && t >= o) v = tot[t - o];
        __syncthreads();
        if (t < NBUCK) tot[t] += v;
        __syncthreads();
    }
    if (t < NBUCK) {
        unsigned excl = tot[t] - run;
        cbase[t] = excl;
        bb[t] = excl;
        if (t == NBUCK - 1) bb[NBUCK] = tot[t];
    }
    __syncthreads();
    u32x4* hm4 = (u32x4*)hmat;
    for (int idx = t; idx < NB * NBUCK / 4; idx += 1024) {
        u32x4 q = hm4[idx];
        unsigned cb = cbase[idx >> 6]; // 64 uint4 per bucket row (NB/4)
        q.x += cb; q.y += cb; q.z += cb; q.w += cb;
        hm4[idx] = q;
    }
}

// Scatter into 512-bucket order: long destination runs (~15 pts) -> good lines.
__global__ __launch_bounds__(BTS) void scatter_k(const float* __restrict__ xyz,
                                                 const int* __restrict__ boundp,
                                                 const unsigned* __restrict__ hmat,
                                                 float4* __restrict__ s1, int N) {
    __shared__ unsigned cnt[NBUCK];
    int b = blockIdx.x;
    for (int i = threadIdx.x; i < NBUCK; i += BTS)
        cnt[i] = hmat[(size_t)i * NB + b];
    __syncthreads();
    float invb = 1.0f / (float)boundp[0];
    int NG = (N + 3) >> 2;
    for (int g = b * BTS + threadIdx.x; g < NG; g += NB * BTS) {
        int n0 = g << 2;
        if (n0 + 4 <= N) {
            f32x4 qa = *(const f32x4*)(xyz + (size_t)n0 * 3);
            f32x4 qb = *(const f32x4*)(xyz + (size_t)n0 * 3 + 4);
            f32x4 qc = *(const f32x4*)(xyz + (size_t)n0 * 3 + 8);
            {
                float x = qa.x * invb, y = qa.y * invb, z = qa.z * invb;
                unsigned d = atomicAdd(&cnt[morton21(x, y, z) >> 12], 1u);
                s1[d] = make_float4(x, y, z, __int_as_float(n0 + 0));
            }
            {
                float x = qa.w * invb, y = qb.x * invb, z = qb.y * invb;
                unsigned d = atomicAdd(&cnt[morton21(x, y, z) >> 12], 1u);
                s1[d] = make_float4(x, y, z, __int_as_float(n0 + 1));
            }
            {
                float x = qb.z * invb, y = qb.w * invb, z = qc.x * invb;
                unsigned d = atomicAdd(&cnt[morton21(x, y, z) >> 12], 1u);
                s1[d] = make_float4(x, y, z, __int_as_float(n0 + 2));
            }
            {
                float x = qc.y * invb, y = qc.z * invb, z = qc.w * invb;
                unsigned d = atomicAdd(&cnt[morton21(x, y, z) >> 12], 1u);
                s1[d] = make_float4(x, y, z, __int_as_float(n0 + 3));
            }
        } else {
            for (int n = n0; n < N; ++n) {
                float x = xyz[(size_t)3 * n + 0] * invb;
                float y = xyz[(size_t)3 * n + 1] * invb;
                float z = xyz[(size_t)3 * n + 2] * invb;
                unsigned d = atomicAdd(&cnt[morton21(x, y, z) >> 12], 1u);
                s1[d] = make_float4(x, y, z, __int_as_float(n));
            }
        }
    }
}

// Per-bucket LDS counting sort by fine 12-bit Morton key -> full 128^3 order.
// Records live in registers; LDS only holds the 4096 counters + scan aux.
__global__ __launch_bounds__(1024) void refine_k(const float4* __restrict__ s1,
                                                 const unsigned* __restrict__ bb,
                                                 float4* __restrict__ s2) {
    __shared__ unsigned hist[4096];
    __shared__ unsigned part[1024];
    int b = blockIdx.x;
    unsigned start = bb[b];
    unsigned cnt = bb[b + 1] - start;
    int t = threadIdx.x;
    if (cnt > RCAP) { // statistically unreachable; correctness fallback
        for (unsigned j = t; j < cnt; j += 1024) s2[start + j] = s1[start + j];
        return;
    }
    for (int i = t; i < 4096; i += 1024) hist[i] = 0u;
    __syncthreads();
    float4 rec[RCAP / 1024];
    unsigned key[RCAP / 1024], tick[RCAP / 1024];
#pragma unroll
    for (int k = 0; k < RCAP / 1024; ++k) {
        unsigned j = t + k * 1024u;
        if (j < cnt) {
            rec[k] = s1[start + j];
            key[k] = morton21(rec[k].x, rec[k].y, rec[k].z) & 4095u;
            tick[k] = atomicAdd(&hist[key[k]], 1u);
        }
    }
    __syncthreads();
    unsigned h4[4];
    unsigned s = 0;
#pragma unroll
    for (int k = 0; k < 4; ++k) {
        h4[k] = hist[t * 4 + k];
        s += h4[k];
    }
    part[t] = s;
    __syncthreads();
    for (int o = 1; o < 1024; o <<= 1) {
        unsigned v = (t >= o) ? part[t - o] : 0u;
        __syncthreads();
        part[t] += v;
        __syncthreads();
    }
    unsigned base = part[t] - s;
#pragma unroll
    for (int k = 0; k < 4; ++k) {
        hist[t * 4 + k] = base;
        base += h4[k];
    }
    __syncthreads();
#pragma unroll
    for (int k = 0; k < RCAP / 1024; ++k) {
        unsigned j = t + k * 1024u;
        if (j < cnt) s2[start + hist[key[k]] + tick[k]] = rec[k];
    }
}

// ---------- main sampler (Morton order, bf16 channels-last tables) ----------
__global__ __launch_bounds__(256) void sample_srt(const float4* __restrict__ sorted,
                                                  const uint4* __restrict__ gclb,
                                                  const uint4* __restrict__ pclb,
                                                  float* __restrict__ out, int N) {
    int i = blockIdx.x * blockDim.x + threadIdx.x;
    if (i >= N) return;
    float4 rec = sorted[i];
    float x = rec.x, y = rec.y, z = rec.z;
    int idx = __float_as_int(rec.w);

    int x0, x1, y0, y1, z0, z1;
    float wx, wy, wz;
    to_idx(x, LRES, x0, x1, wx);
    to_idx(y, LRES, y0, y1, wy);
    to_idx(z, LRES, z0, z1, wz);
    const uint4* b00 = gclb + ((size_t)z0 * LRES + y0) * LRES;
    const uint4* b01 = gclb + ((size_t)z0 * LRES + y1) * LRES;
    const uint4* b10 = gclb + ((size_t)z1 * LRES + y0) * LRES;
    const uint4* b11 = gclb + ((size_t)z1 * LRES + y1) * LRES;
    uint4 g0 = b00[x0], g1 = b00[x1], g2 = b01[x0], g3 = b01[x1];
    uint4 g4 = b10[x0], g5 = b10[x1], g6 = b11[x0], g7 = b11[x1];

    const float cw[3] = {x, y, z};
    const float ch[3] = {y, z, x};
    float pww[3], pwh[3];
    uint4 r[12];
#pragma unroll
    for (int p = 0; p < 3; ++p) {
        int w0, w1, h0, h1;
        to_idx(cw[p], HRES, w0, w1, pww[p]);
        to_idx(ch[p], HRES, h0, h1, pwh[p]);
        const uint4* base = pclb + (size_t)p * PPIX;
        const uint4* r0 = base + (size_t)h0 * HRES;
        const uint4* r1 = base + (size_t)h1 * HRES;
        r[4 * p + 0] = r0[w0];
        r[4 * p + 1] = r0[w1];
        r[4 * p + 2] = r1[w0];
        r[4 * p + 3] = r1[w1];
    }

    f32x4 a0 = (f32x4)0.f;
    f32x4 a1 = (f32x4)0.f;
    {
        float ux = 1.f - wx, uy = 1.f - wy, uz = 1.f - wz;
        fma8u(a0, a1, g0, uz * uy * ux);
        fma8u(a0, a1, g1, uz * uy * wx);
        fma8u(a0, a1, g2, uz * wy * ux);
        fma8u(a0, a1, g3, uz * wy * wx);
        fma8u(a0, a1, g4, wz * uy * ux);
        fma8u(a0, a1, g5, wz * uy * wx);
        fma8u(a0, a1, g6, wz * wy * ux);
        fma8u(a0, a1, g7, wz * wy * wx);
    }
#pragma unroll
    for (int p = 0; p < 3; ++p) {
        float ww = pww[p], wh = pwh[p];
        float uw = 1.f - ww, uh = 1.f - wh;
        fma8u(a0, a1, r[4 * p + 0], uh * uw);
        fma8u(a0, a1, r[4 * p + 1], uh * ww);
        fma8u(a0, a1, r[4 * p + 2], wh * uw);
        fma8u(a0, a1, r[4 * p + 3], wh * ww);
    }

    f32x4* o = (f32x4*)(out + (size_t)idx * 8);
    o[0] = a0;
    o[1] = a1;
}

// ---------- fallback (channel-first fp32 direct, known-correct) ----------
__global__ __launch_bounds__(256) void sample_cf(
    const float* __restrict__ xyz, const int* __restrict__ boundp,
    const float* __restrict__ Lg, const float* __restrict__ Hp,
    float* __restrict__ out, int N) {
    int n = blockIdx.x * blockDim.x + threadIdx.x;
    if (n >= N) return;
    float invb = 1.0f / (float)boundp[0];
    float x = xyz[(size_t)3 * n + 0] * invb;
    float y = xyz[(size_t)3 * n + 1] * invb;
    float z = xyz[(size_t)3 * n + 2] * invb;
    float acc[8];
#pragma unroll
    for (int c = 0; c < 8; ++c) acc[c] = 0.f;
    {
        int x0, x1, y0, y1, z0, z1;
        float wx, wy, wz;
        to_idx(x, LRES, x0, x1, wx);
        to_idx(y, LRES, y0, y1, wy);
        to_idx(z, LRES, z0, z1, wz);
        float ux = 1.f - wx, uy = 1.f - wy, uz = 1.f - wz;
        size_t i8[8];
        i8[0] = ((size_t)z0 * LRES + y0) * LRES + x0;
        i8[1] = ((size_t)z0 * LRES + y0) * LRES + x1;
        i8[2] = ((size_t)z0 * LRES + y1) * LRES + x0;
        i8[3] = ((size_t)z0 * LRES + y1) * LRES + x1;
        i8[4] = ((size_t)z1 * LRES + y0) * LRES + x0;
        i8[5] = ((size_t)z1 * LRES + y0) * LRES + x1;
        i8[6] = ((size_t)z1 * LRES + y1) * LRES + x0;
        i8[7] = ((size_t)z1 * LRES + y1) * LRES + x1;
        float w8[8] = {uz * uy * ux, uz * uy * wx, uz * wy * ux, uz * wy * wx,
                       wz * uy * ux, wz * uy * wx, wz * wy * ux, wz * wy * wx};
#pragma unroll
        for (int c = 0; c < 8; ++c) {
            const float* g = Lg + (size_t)c * LVOX;
            float s = 0.f;
#pragma unroll
            for (int k = 0; k < 8; ++k) s = fmaf(g[i8[k]], w8[k], s);
            acc[c] += s;
        }
    }
    {
        const float cw[3] = {x, y, z};
        const float ch[3] = {y, z, x};
        for (int p = 0; p < 3; ++p) {
            int w0, w1, h0, h1;
            float ww, wh;
            to_idx(cw[p], HRES, w0, w1, ww);
            to_idx(ch[p], HRES, h0, h1, wh);
            float uw = 1.f - ww, uh = 1.f - wh;
            size_t i4[4] = {(size_t)h0 * HRES + w0, (size_t)h0 * HRES + w1,
                            (size_t)h1 * HRES + w0, (size_t)h1 * HRES + w1};
            float w4[4] = {uh * uw, uh * ww, wh * uw, wh * ww};
            const float* pb = Hp + (size_t)p * 8 * PPIX;
#pragma unroll
            for (int c = 0; c < 8; ++c) {
                const float* g = pb + (size_t)c * PPIX;
                float s = 0.f;
#pragma unroll
                for (int k = 0; k < 4; ++k) s = fmaf(g[i4[k]], w4[k], s);
                acc[c] += s;
            }
        }
    }
#pragma unroll
    for (int c = 0; c < 8; ++c) out[(size_t)n * 8 + c] = acc[c];
}

extern "C" void kernel_launch(void* const* d_in, const int* in_sizes, int n_in,
                              void* d_out, int out_size, void* d_ws, size_t ws_size,
                              hipStream_t stream) {
    const float* xyz = (const float*)d_in[0];
    const int* bound = (const int*)d_in[1];
    const float* Lg = (const float*)d_in[2]; // [8,128,128,128]
    const float* Hp = (const float*)d_in[3]; // [3,8,1024,1024]
    float* out = (float*)d_out;
    int N = in_sizes[0] / 3;

    size_t off = 0;
    size_t gclb_b = (size_t)LVOX * 16;         // 32 MiB
    size_t pclb_b = (size_t)3 * PPIX * 16;     // 48 MiB
    size_t s1_b = (size_t)N * 16;              // 32 MB
    size_t s2_b = (size_t)N * 16;              // 32 MB
    size_t hmat_b = (size_t)NB * NBUCK * 4;    // 512 KiB
    size_t bb_b = (size_t)(NBUCK + 1) * 4;
    size_t need = gclb_b + pclb_b + s1_b + s2_b + hmat_b + bb_b;

    if (ws_size >= need) {
        char* w = (char*)d_ws;
        u32x4* gclb = (u32x4*)(w + off);       off += gclb_b;
        u32x4* pclb = (u32x4*)(w + off);       off += pclb_b;
        float4* s1 = (float4*)(w + off);       off += s1_b;
        float4* s2 = (float4*)(w + off);       off += s2_b;
        unsigned* hmat = (unsigned*)(w + off); off += hmat_b;
        unsigned* bb = (unsigned*)(w + off);

        int prep_blocks = NB + (TV / 4 + BTS - 1) / BTS; // 256 + 1280
        prep_k<<<prep_blocks, BTS, 0, stream>>>(xyz, bound, Lg, Hp, hmat, gclb, pclb, N);
        offsets_k<<<1, 1024, 0, stream>>>(hmat, bb);
        scatter_k<<<NB, BTS, 0, stream>>>(xyz, bound, hmat, s1, N);
        refine_k<<<NBUCK, 1024, 0, stream>>>(s1, bb, s2);
        sample_srt<<<(N + 255) / 256, 256, 0, stream>>>(s2, (const uint4*)gclb,
                                                        (const uint4*)pclb, out, N);
    } else {
        sample_cf<<<(N + 255) / 256, 256, 0, stream>>>(xyz, bound, Lg, Hp, out, N);
    }
}

// Round 2
// 428.228 us; speedup vs baseline: 1.1623x; 1.1623x over previous
//
#include <hip/hip_runtime.h>

#define LRES 128
#define HRES 1024
#define NB 256        // hist/scatter blocks
#define BTS 1024      // threads for big blocks
#define NBUCK 512     // coarse buckets (Morton top 9 bits of 128^3 lattice)
#define RCAP 8192     // refine in-register cap per bucket (avg ~3906)
#define TELEM 2048    // transpose tile elems (exactly divides LVOX and PPIX)

static const int LVOX = LRES * LRES * LRES; // 2,097,152
static const int PPIX = HRES * HRES;        // 1,048,576
static const int TV = LVOX + 3 * PPIX;      // 5,242,880 transpose elems

typedef float f32x4 __attribute__((ext_vector_type(4)));
typedef unsigned u32x4 __attribute__((ext_vector_type(4)));

// ---------- helpers ----------

// Replicates reference _to_idx exactly.
__device__ __forceinline__ void to_idx(float c, int size, int& i0, int& i1, float& w) {
    float p = (c + 1.0f) * 0.5f * (float)(size - 1);
    float f = floorf(p);
    w = p - f;
    int i = (int)f;
    i0 = min(max(i, 0), size - 1);
    i1 = min(i0 + 1, size - 1);
}

// float -> bf16 (RNE)
__device__ __forceinline__ unsigned f2bf(float f) {
    unsigned u = __float_as_uint(f);
    return (u + 0x7FFFu + ((u >> 16) & 1u)) >> 16;
}
__device__ __forceinline__ float bflo(unsigned u) { return __uint_as_float(u << 16); }
__device__ __forceinline__ float bfhi(unsigned u) { return __uint_as_float(u & 0xFFFF0000u); }

__device__ __forceinline__ void fma8u(f32x4& a0, f32x4& a1, uint4 q, float w) {
    a0.x = fmaf(bflo(q.x), w, a0.x);
    a0.y = fmaf(bfhi(q.x), w, a0.y);
    a0.z = fmaf(bflo(q.y), w, a0.z);
    a0.w = fmaf(bfhi(q.y), w, a0.w);
    a1.x = fmaf(bflo(q.z), w, a1.x);
    a1.y = fmaf(bfhi(q.z), w, a1.y);
    a1.z = fmaf(bflo(q.w), w, a1.z);
    a1.w = fmaf(bfhi(q.w), w, a1.w);
}

__device__ __forceinline__ unsigned spread3(unsigned x) {
    x &= 0x3FFu;
    x = (x | (x << 16)) & 0x030000FFu;
    x = (x | (x << 8)) & 0x0300F00Fu;
    x = (x | (x << 4)) & 0x030C30C3u;
    x = (x | (x << 2)) & 0x09249249u;
    return x;
}
// 21-bit Morton on a 128^3 lattice over [0,1)^3. bucket = >>12, fine = &4095.
__device__ __forceinline__ unsigned morton21(float x, float y, float z) {
    int px = min(max((int)(x * 128.f), 0), 127);
    int py = min(max((int)(y * 128.f), 0), 127);
    int pz = min(max((int)(z * 128.f), 0), 127);
    return spread3(px) | (spread3(py) << 1) | (spread3(pz) << 2);
}

// async 16B global->LDS (direct DMA, vmcnt-tracked; LDS dest = wave base + lane*16)
__device__ __forceinline__ void gl_lds16(const float* src, float* lds_dst) {
    __builtin_amdgcn_global_load_lds(
        (const __attribute__((address_space(1))) void*)src,
        (__attribute__((address_space(3))) void*)lds_dst, 16, 0, 0);
}

// ---------- fused prep: blocks [0,NB) = bucket histogram, rest = transpose ----------
// hmat is BUCKET-major: hmat[c * NB + b] (contiguous per-bucket rows for the scan).
// Transpose: LDS-staged via global_load_lds so MLP does not depend on regalloc;
// every global load AND store instruction is 1KB-contiguous per wave.
__global__ __launch_bounds__(BTS) void prep_k(const float* __restrict__ xyz,
                                              const int* __restrict__ boundp,
                                              const float* __restrict__ Lg,
                                              const float* __restrict__ Hp,
                                              unsigned* __restrict__ hmat,
                                              u32x4* __restrict__ gclb,
                                              u32x4* __restrict__ pclb, int N) {
    __shared__ float stage[8 * TELEM]; // 64 KB; hist branch aliases first 2KB
    int b = blockIdx.x;
    if (b < NB) {
        unsigned* h = (unsigned*)stage;
        for (int i = threadIdx.x; i < NBUCK; i += BTS) h[i] = 0u;
        __syncthreads();
        float invb = 1.0f / (float)boundp[0];
        int NG = (N + 3) >> 2; // 4-point groups
        for (int g = b * BTS + threadIdx.x; g < NG; g += NB * BTS) {
            int n0 = g << 2;
            if (n0 + 4 <= N) {
                f32x4 qa = *(const f32x4*)(xyz + (size_t)n0 * 3);
                f32x4 qb = *(const f32x4*)(xyz + (size_t)n0 * 3 + 4);
                f32x4 qc = *(const f32x4*)(xyz + (size_t)n0 * 3 + 8);
                atomicAdd(&h[morton21(qa.x * invb, qa.y * invb, qa.z * invb) >> 12], 1u);
                atomicAdd(&h[morton21(qa.w * invb, qb.x * invb, qb.y * invb) >> 12], 1u);
                atomicAdd(&h[morton21(qb.z * invb, qb.w * invb, qc.x * invb) >> 12], 1u);
                atomicAdd(&h[morton21(qc.y * invb, qc.z * invb, qc.w * invb) >> 12], 1u);
            } else {
                for (int n = n0; n < N; ++n) {
                    float x = xyz[(size_t)3 * n + 0] * invb;
                    float y = xyz[(size_t)3 * n + 1] * invb;
                    float z = xyz[(size_t)3 * n + 2] * invb;
                    atomicAdd(&h[morton21(x, y, z) >> 12], 1u);
                }
            }
        }
        __syncthreads();
        for (int i = threadIdx.x; i < NBUCK; i += BTS)
            hmat[(size_t)i * NB + b] = h[i];
    } else {
        // ---- LDS-staged transpose tile: TELEM contiguous channels-last elems ----
        int tb = b - NB;
        size_t vbase = (size_t)tb * TELEM;
        const float* srcbase;
        size_t cstride;
        u32x4* dst;
        if (vbase < (size_t)LVOX) { // tiles never straddle (TELEM | LVOX, PPIX)
            srcbase = Lg + vbase;
            cstride = LVOX;
            dst = gclb + vbase;
        } else {
            size_t u = vbase - LVOX;
            int p = (int)(u >> 20); // PPIX = 2^20
            size_t r = u & (size_t)(PPIX - 1);
            srcbase = Hp + (size_t)p * 8 * PPIX + r;
            cstride = PPIX;
            dst = pclb + (size_t)p * PPIX + r;
        }
        // Stage 8 ch x TELEM f32 = 64KB as 64 wave-chunks of 1KB.
        // chunk k: channel c = k>>3, sub s = k&7; lane dest = k*1024 + lane*16.
        int wave = threadIdx.x >> 6;
        int lane = threadIdx.x & 63;
        for (int k = wave; k < 64; k += 16) {
            int c = k >> 3, s = k & 7;
            gl_lds16(srcbase + (size_t)c * cstride + s * 256 + lane * 4,
                     &stage[k * 256]);
        }
        __syncthreads(); // drains vmcnt (compiler emits vmcnt(0) before barrier)
        int t = threadIdx.x;
#pragma unroll
        for (int e = 0; e < TELEM / BTS; ++e) {
            int v = e * BTS + t;
            unsigned hc[8];
#pragma unroll
            for (int c = 0; c < 8; ++c) hc[c] = f2bf(stage[c * TELEM + v]);
            u32x4 o;
            o.x = hc[0] | (hc[1] << 16);
            o.y = hc[2] | (hc[3] << 16);
            o.z = hc[4] | (hc[5] << 16);
            o.w = hc[6] | (hc[7] << 16);
            dst[v] = o; // 1KB contiguous per wave store; stays L2/L3-hot for sampler
        }
    }
}

// Single block: cross-block prefix per bucket (in place, bucket-major rows so
// each thread streams a contiguous 1KB row via uint4 with 8 loads in flight),
// scan bucket totals, emit bucket_base[NBUCK+1], add base into hmat.
__global__ __launch_bounds__(1024) void offsets_k(unsigned* __restrict__ hmat,
                                                  unsigned* __restrict__ bb) {
    __shared__ unsigned tot[NBUCK];
    __shared__ unsigned cbase[NBUCK];
    int t = threadIdx.x;
    unsigned run = 0;
    if (t < NBUCK) {
        u32x4* row = (u32x4*)(hmat + (size_t)t * NB);
        for (int ch = 0; ch < NB / 32; ++ch) { // 8 chunks of 8 uint4 = 256 vals
            u32x4 q[8];
#pragma unroll
            for (int k = 0; k < 8; ++k) q[k] = row[ch * 8 + k];
#pragma unroll
            for (int k = 0; k < 8; ++k) {
                unsigned v0 = q[k].x, v1 = q[k].y, v2 = q[k].z, v3 = q[k].w;
                q[k].x = run; run += v0;
                q[k].y = run; run += v1;
                q[k].z = run; run += v2;
                q[k].w = run; run += v3;
                row[ch * 8 + k] = q[k];
            }
        }
        tot[t] = run;
    }
    __syncthreads();
    for (int o = 1; o < NBUCK; o <<= 1) {
        unsigned v = 0;
        if (t < NBUCK && t >= o) v = tot[t - o];
        __syncthreads();
        if (t < NBUCK) tot[t] += v;
        __syncthreads();
    }
    if (t < NBUCK) {
        unsigned excl = tot[t] - run;
        cbase[t] = excl;
        bb[t] = excl;
        if (t == NBUCK - 1) bb[NBUCK] = tot[t];
    }
    __syncthreads();
    u32x4* hm4 = (u32x4*)hmat;
    for (int idx = t; idx < NB * NBUCK / 4; idx += 1024) {
        u32x4 q = hm4[idx];
        unsigned cb = cbase[idx >> 6]; // 64 uint4 per bucket row (NB/4)
        q.x += cb; q.y += cb; q.z += cb; q.w += cb;
        hm4[idx] = q;
    }
}

// Scatter into 512-bucket order: long destination runs (~15 pts) -> good lines.
__global__ __launch_bounds__(BTS) void scatter_k(const float* __restrict__ xyz,
                                                 const int* __restrict__ boundp,
                                                 const unsigned* __restrict__ hmat,
                                                 float4* __restrict__ s1, int N) {
    __shared__ unsigned cnt[NBUCK];
    int b = blockIdx.x;
    for (int i = threadIdx.x; i < NBUCK; i += BTS)
        cnt[i] = hmat[(size_t)i * NB + b];
    __syncthreads();
    float invb = 1.0f / (float)boundp[0];
    int NG = (N + 3) >> 2;
    for (int g = b * BTS + threadIdx.x; g < NG; g += NB * BTS) {
        int n0 = g << 2;
        if (n0 + 4 <= N) {
            f32x4 qa = *(const f32x4*)(xyz + (size_t)n0 * 3);
            f32x4 qb = *(const f32x4*)(xyz + (size_t)n0 * 3 + 4);
            f32x4 qc = *(const f32x4*)(xyz + (size_t)n0 * 3 + 8);
            {
                float x = qa.x * invb, y = qa.y * invb, z = qa.z * invb;
                unsigned d = atomicAdd(&cnt[morton21(x, y, z) >> 12], 1u);
                s1[d] = make_float4(x, y, z, __int_as_float(n0 + 0));
            }
            {
                float x = qa.w * invb, y = qb.x * invb, z = qb.y * invb;
                unsigned d = atomicAdd(&cnt[morton21(x, y, z) >> 12], 1u);
                s1[d] = make_float4(x, y, z, __int_as_float(n0 + 1));
            }
            {
                float x = qb.z * invb, y = qb.w * invb, z = qc.x * invb;
                unsigned d = atomicAdd(&cnt[morton21(x, y, z) >> 12], 1u);
                s1[d] = make_float4(x, y, z, __int_as_float(n0 + 2));
            }
            {
                float x = qc.y * invb, y = qc.z * invb, z = qc.w * invb;
                unsigned d = atomicAdd(&cnt[morton21(x, y, z) >> 12], 1u);
                s1[d] = make_float4(x, y, z, __int_as_float(n0 + 3));
            }
        } else {
            for (int n = n0; n < N; ++n) {
                float x = xyz[(size_t)3 * n + 0] * invb;
                float y = xyz[(size_t)3 * n + 1] * invb;
                float z = xyz[(size_t)3 * n + 2] * invb;
                unsigned d = atomicAdd(&cnt[morton21(x, y, z) >> 12], 1u);
                s1[d] = make_float4(x, y, z, __int_as_float(n));
            }
        }
    }
}

// Per-bucket LDS counting sort by fine 12-bit Morton key -> full 128^3 order.
// Records live in registers; LDS only holds the 4096 counters + scan aux.
__global__ __launch_bounds__(1024) void refine_k(const float4* __restrict__ s1,
                                                 const unsigned* __restrict__ bb,
                                                 float4* __restrict__ s2) {
    __shared__ unsigned hist[4096];
    __shared__ unsigned part[1024];
    int b = blockIdx.x;
    unsigned start = bb[b];
    unsigned cnt = bb[b + 1] - start;
    int t = threadIdx.x;
    if (cnt > RCAP) { // statistically unreachable; correctness fallback
        for (unsigned j = t; j < cnt; j += 1024) s2[start + j] = s1[start + j];
        return;
    }
    for (int i = t; i < 4096; i += 1024) hist[i] = 0u;
    __syncthreads();
    float4 rec[RCAP / 1024];
    unsigned key[RCAP / 1024], tick[RCAP / 1024];
#pragma unroll
    for (int k = 0; k < RCAP / 1024; ++k) {
        unsigned j = t + k * 1024u;
        if (j < cnt) {
            rec[k] = s1[start + j];
            key[k] = morton21(rec[k].x, rec[k].y, rec[k].z) & 4095u;
            tick[k] = atomicAdd(&hist[key[k]], 1u);
        }
    }
    __syncthreads();
    unsigned h4[4];
    unsigned s = 0;
#pragma unroll
    for (int k = 0; k < 4; ++k) {
        h4[k] = hist[t * 4 + k];
        s += h4[k];
    }
    part[t] = s;
    __syncthreads();
    for (int o = 1; o < 1024; o <<= 1) {
        unsigned v = (t >= o) ? part[t - o] : 0u;
        __syncthreads();
        part[t] += v;
        __syncthreads();
    }
    unsigned base = part[t] - s;
#pragma unroll
    for (int k = 0; k < 4; ++k) {
        hist[t * 4 + k] = base;
        base += h4[k];
    }
    __syncthreads();
#pragma unroll
    for (int k = 0; k < RCAP / 1024; ++k) {
        unsigned j = t + k * 1024u;
        if (j < cnt) s2[start + hist[key[k]] + tick[k]] = rec[k];
    }
}

// ---------- main sampler (Morton order, bf16 channels-last tables) ----------
__global__ __launch_bounds__(256) void sample_srt(const float4* __restrict__ sorted,
                                                  const uint4* __restrict__ gclb,
                                                  const uint4* __restrict__ pclb,
                                                  float* __restrict__ out, int N) {
    int i = blockIdx.x * blockDim.x + threadIdx.x;
    if (i >= N) return;
    float4 rec = sorted[i];
    float x = rec.x, y = rec.y, z = rec.z;
    int idx = __float_as_int(rec.w);

    int x0, x1, y0, y1, z0, z1;
    float wx, wy, wz;
    to_idx(x, LRES, x0, x1, wx);
    to_idx(y, LRES, y0, y1, wy);
    to_idx(z, LRES, z0, z1, wz);
    const uint4* b00 = gclb + ((size_t)z0 * LRES + y0) * LRES;
    const uint4* b01 = gclb + ((size_t)z0 * LRES + y1) * LRES;
    const uint4* b10 = gclb + ((size_t)z1 * LRES + y0) * LRES;
    const uint4* b11 = gclb + ((size_t)z1 * LRES + y1) * LRES;
    uint4 g0 = b00[x0], g1 = b00[x1], g2 = b01[x0], g3 = b01[x1];
    uint4 g4 = b10[x0], g5 = b10[x1], g6 = b11[x0], g7 = b11[x1];

    const float cw[3] = {x, y, z};
    const float ch[3] = {y, z, x};
    float pww[3], pwh[3];
    uint4 r[12];
#pragma unroll
    for (int p = 0; p < 3; ++p) {
        int w0, w1, h0, h1;
        to_idx(cw[p], HRES, w0, w1, pww[p]);
        to_idx(ch[p], HRES, h0, h1, pwh[p]);
        const uint4* base = pclb + (size_t)p * PPIX;
        const uint4* r0 = base + (size_t)h0 * HRES;
        const uint4* r1 = base + (size_t)h1 * HRES;
        r[4 * p + 0] = r0[w0];
        r[4 * p + 1] = r0[w1];
        r[4 * p + 2] = r1[w0];
        r[4 * p + 3] = r1[w1];
    }

    f32x4 a0 = (f32x4)0.f;
    f32x4 a1 = (f32x4)0.f;
    {
        float ux = 1.f - wx, uy = 1.f - wy, uz = 1.f - wz;
        fma8u(a0, a1, g0, uz * uy * ux);
        fma8u(a0, a1, g1, uz * uy * wx);
        fma8u(a0, a1, g2, uz * wy * ux);
        fma8u(a0, a1, g3, uz * wy * wx);
        fma8u(a0, a1, g4, wz * uy * ux);
        fma8u(a0, a1, g5, wz * uy * wx);
        fma8u(a0, a1, g6, wz * wy * ux);
        fma8u(a0, a1, g7, wz * wy * wx);
    }
#pragma unroll
    for (int p = 0; p < 3; ++p) {
        float ww = pww[p], wh = pwh[p];
        float uw = 1.f - ww, uh = 1.f - wh;
        fma8u(a0, a1, r[4 * p + 0], uh * uw);
        fma8u(a0, a1, r[4 * p + 1], uh * ww);
        fma8u(a0, a1, r[4 * p + 2], wh * uw);
        fma8u(a0, a1, r[4 * p + 3], wh * ww);
    }

    f32x4* o = (f32x4*)(out + (size_t)idx * 8);
    o[0] = a0;
    o[1] = a1;
}

// ---------- fallback (channel-first fp32 direct, known-correct) ----------
__global__ __launch_bounds__(256) void sample_cf(
    const float* __restrict__ xyz, const int* __restrict__ boundp,
    const float* __restrict__ Lg, const float* __restrict__ Hp,
    float* __restrict__ out, int N) {
    int n = blockIdx.x * blockDim.x + threadIdx.x;
    if (n >= N) return;
    float invb = 1.0f / (float)boundp[0];
    float x = xyz[(size_t)3 * n + 0] * invb;
    float y = xyz[(size_t)3 * n + 1] * invb;
    float z = xyz[(size_t)3 * n + 2] * invb;
    float acc[8];
#pragma unroll
    for (int c = 0; c < 8; ++c) acc[c] = 0.f;
    {
        int x0, x1, y0, y1, z0, z1;
        float wx, wy, wz;
        to_idx(x, LRES, x0, x1, wx);
        to_idx(y, LRES, y0, y1, wy);
        to_idx(z, LRES, z0, z1, wz);
        float ux = 1.f - wx, uy = 1.f - wy, uz = 1.f - wz;
        size_t i8[8];
        i8[0] = ((size_t)z0 * LRES + y0) * LRES + x0;
        i8[1] = ((size_t)z0 * LRES + y0) * LRES + x1;
        i8[2] = ((size_t)z0 * LRES + y1) * LRES + x0;
        i8[3] = ((size_t)z0 * LRES + y1) * LRES + x1;
        i8[4] = ((size_t)z1 * LRES + y0) * LRES + x0;
        i8[5] = ((size_t)z1 * LRES + y0) * LRES + x1;
        i8[6] = ((size_t)z1 * LRES + y1) * LRES + x0;
        i8[7] = ((size_t)z1 * LRES + y1) * LRES + x1;
        float w8[8] = {uz * uy * ux, uz * uy * wx, uz * wy * ux, uz * wy * wx,
                       wz * uy * ux, wz * uy * wx, wz * wy * ux, wz * wy * wx};
#pragma unroll
        for (int c = 0; c < 8; ++c) {
            const float* g = Lg + (size_t)c * LVOX;
            float s = 0.f;
#pragma unroll
            for (int k = 0; k < 8; ++k) s = fmaf(g[i8[k]], w8[k], s);
            acc[c] += s;
        }
    }
    {
        const float cw[3] = {x, y, z};
        const float ch[3] = {y, z, x};
        for (int p = 0; p < 3; ++p) {
            int w0, w1, h0, h1;
            float ww, wh;
            to_idx(cw[p], HRES, w0, w1, ww);
            to_idx(ch[p], HRES, h0, h1, wh);
            float uw = 1.f - ww, uh = 1.f - wh;
            size_t i4[4] = {(size_t)h0 * HRES + w0, (size_t)h0 * HRES + w1,
                            (size_t)h1 * HRES + w0, (size_t)h1 * HRES + w1};
            float w4[4] = {uh * uw, uh * ww, wh * uw, wh * ww};
            const float* pb = Hp + (size_t)p * 8 * PPIX;
#pragma unroll
            for (int c = 0; c < 8; ++c) {
                const float* g = pb + (size_t)c * PPIX;
                float s = 0.f;
#pragma unroll
                for (int k = 0; k < 4; ++k) s = fmaf(g[i4[k]], w4[k], s);
                acc[c] += s;
            }
        }
    }
#pragma unroll
    for (int c = 0; c < 8; ++c) out[(size_t)n * 8 + c] = acc[c];
}

extern "C" void kernel_launch(void* const* d_in, const int* in_sizes, int n_in,
                              void* d_out, int out_size, void* d_ws, size_t ws_size,
                              hipStream_t stream) {
    const float* xyz = (const float*)d_in[0];
    const int* bound = (const int*)d_in[1];
    const float* Lg = (const float*)d_in[2]; // [8,128,128,128]
    const float* Hp = (const float*)d_in[3]; // [3,8,1024,1024]
    float* out = (float*)d_out;
    int N = in_sizes[0] / 3;

    size_t off = 0;
    size_t gclb_b = (size_t)LVOX * 16;         // 32 MiB
    size_t pclb_b = (size_t)3 * PPIX * 16;     // 48 MiB
    size_t s1_b = (size_t)N * 16;              // 32 MB
    size_t s2_b = (size_t)N * 16;              // 32 MB
    size_t hmat_b = (size_t)NB * NBUCK * 4;    // 512 KiB
    size_t bb_b = (size_t)(NBUCK + 1) * 4;
    size_t need = gclb_b + pclb_b + s1_b + s2_b + hmat_b + bb_b;

    if (ws_size >= need) {
        char* w = (char*)d_ws;
        u32x4* gclb = (u32x4*)(w + off);       off += gclb_b;
        u32x4* pclb = (u32x4*)(w + off);       off += pclb_b;
        float4* s1 = (float4*)(w + off);       off += s1_b;
        float4* s2 = (float4*)(w + off);       off += s2_b;
        unsigned* hmat = (unsigned*)(w + off); off += hmat_b;
        unsigned* bb = (unsigned*)(w + off);

        int prep_blocks = NB + TV / TELEM; // 256 + 2560
        prep_k<<<prep_blocks, BTS, 0, stream>>>(xyz, bound, Lg, Hp, hmat, gclb, pclb, N);
        offsets_k<<<1, 1024, 0, stream>>>(hmat, bb);
        scatter_k<<<NB, BTS, 0, stream>>>(xyz, bound, hmat, s1, N);
        refine_k<<<NBUCK, 1024, 0, stream>>>(s1, bb, s2);
        sample_srt<<<(N + 255) / 256, 256, 0, stream>>>(s2, (const uint4*)gclb,
                                                        (const uint4*)pclb, out, N);
    } else {
        sample_cf<<<(N + 255) / 256, 256, 0, stream>>>(xyz, bound, Lg, Hp, out, N);
    }
}